// Round 11
// baseline (337.798 us; speedup 1.0000x reference)
//
#include <hip/hip_runtime.h>
#include <hip/hip_fp16.h>

#define DIM 64
#define BIN_SHIFT 8
#define BINSZ 256      // nodes per bin
#define MAXBINS 512    // supports N up to 131072
#define PB 256         // edge-slice blocks for hist/bucket (power of 2)
#define PB_LOG 8

// ---------------- pass 1: per-block LDS histogram -> C[blk][bin] ----------------

__global__ __launch_bounds__(256) void k_hist(const int* __restrict__ dst,
                                              int* __restrict__ C, int E, int NB) {
    __shared__ int h[MAXBINS];
    for (int i = threadIdx.x; i < NB; i += 256) h[i] = 0;
    __syncthreads();
    int per = (E + PB - 1) / PB;
    int e0 = blockIdx.x * per;
    int e1 = e0 + per; if (e1 > E) e1 = E;
    for (int e = e0 + (int)threadIdx.x; e < e1; e += 256)
        atomicAdd(&h[dst[e] >> BIN_SHIFT], 1);
    __syncthreads();
    for (int i = threadIdx.x; i < NB; i += 256)
        C[blockIdx.x * NB + i] = h[i];
}

// ---------------- pass 2: exclusive scan of C in bin-major logical order ----------------

__global__ __launch_bounds__(1024) void k_scanA(const int* __restrict__ C,
                                                int* __restrict__ S,
                                                int* __restrict__ bsums, int NB, int M) {
    __shared__ int sh[1024];
    int tid = threadIdx.x;
    int j0 = blockIdx.x * 4096 + tid * 4;
    int v[4]; int sum = 0;
#pragma unroll
    for (int t = 0; t < 4; ++t) {
        int j = j0 + t; int x = 0;
        if (j < M) { int bin = j >> PB_LOG, blk = j & (PB - 1); x = C[blk * NB + bin]; }
        v[t] = sum; sum += x;
    }
    sh[tid] = sum;
    __syncthreads();
#pragma unroll
    for (int d = 1; d < 1024; d <<= 1) {
        int t = (tid >= d) ? sh[tid - d] : 0;
        __syncthreads();
        sh[tid] += t;
        __syncthreads();
    }
    int excl = sh[tid] - sum;
#pragma unroll
    for (int t = 0; t < 4; ++t) {
        int j = j0 + t;
        if (j < M) S[j] = excl + v[t];
    }
    if (tid == 1023) bsums[blockIdx.x] = sh[1023];
}

__global__ __launch_bounds__(1024) void k_scanB(int* __restrict__ bsums, int nb) {
    __shared__ int s[1024];
    int tid = threadIdx.x;
    int v = (tid < nb) ? bsums[tid] : 0;
    s[tid] = v;
    __syncthreads();
#pragma unroll
    for (int d = 1; d < 1024; d <<= 1) {
        int t = (tid >= d) ? s[tid - d] : 0;
        __syncthreads();
        s[tid] += t;
        __syncthreads();
    }
    if (tid < nb) bsums[tid] = s[tid] - v;
}

__global__ __launch_bounds__(1024) void k_scanC(int* __restrict__ S,
                                                const int* __restrict__ bsums,
                                                int* __restrict__ binoff,
                                                int NB, int M, int E) {
    int tid = threadIdx.x;
    int j0 = blockIdx.x * 4096 + tid * 4;
    int add = bsums[blockIdx.x];
#pragma unroll
    for (int t = 0; t < 4; ++t) {
        int j = j0 + t;
        if (j < M) {
            int val = S[j] + add;
            S[j] = val;
            if ((j & (PB - 1)) == 0) binoff[j >> PB_LOG] = val;
        }
    }
    if (blockIdx.x == 0 && tid == 0) binoff[NB] = E;
}

// ---------------- pass 3: one-pass bucket scatter, LDS cursors ----------------

__global__ __launch_bounds__(256) void k_bucket(const int* __restrict__ src,
                                                const int* __restrict__ dst,
                                                const int* __restrict__ S,
                                                int* __restrict__ bkt, int E, int NB) {
    __shared__ int lcur[MAXBINS];
    int blk = blockIdx.x;
    for (int i = threadIdx.x; i < NB; i += 256)
        lcur[i] = S[i * PB + blk];
    __syncthreads();
    int per = (E + PB - 1) / PB;
    int e0 = blk * per;
    int e1 = e0 + per; if (e1 > E) e1 = E;
    for (int e = e0 + (int)threadIdx.x; e < e1; e += 256) {
        int d = dst[e];
        int pos = atomicAdd(&lcur[d >> BIN_SHIFT], 1);
        bkt[pos] = src[e] | ((d & (BINSZ - 1)) << 24);
    }
}

// ---------------- pass 4: per-bin counting sort -> csr, off, dinv; + gbound fused ----------------

__global__ __launch_bounds__(256) void k_binsort(const int* __restrict__ bkt,
                                                 const int* __restrict__ binoff,
                                                 int* __restrict__ csr,
                                                 int* __restrict__ off,
                                                 float* __restrict__ dinv,
                                                 const int* __restrict__ batch,
                                                 int* __restrict__ goff,
                                                 int N, int G, int E) {
    __shared__ int cnt[BINSZ], bas[BINSZ], cur[BINSZ];
    int tid = threadIdx.x;
    int b = blockIdx.x;
    int s0 = binoff[b], s1 = binoff[b + 1];
    cnt[tid] = 0; cur[tid] = 0;
    __syncthreads();
    for (int i = s0 + tid; i < s1; i += 256)
        atomicAdd(&cnt[(bkt[i] >> 24) & 255], 1);
    __syncthreads();
    int my = cnt[tid];
    bas[tid] = my;
    __syncthreads();
#pragma unroll
    for (int d = 1; d < 256; d <<= 1) {
        int t = (tid >= d) ? bas[tid - d] : 0;
        __syncthreads();
        bas[tid] += t;
        __syncthreads();
    }
    int ex = bas[tid] - my;
    __syncthreads();
    bas[tid] = ex;
    {
        int v = (b << BIN_SHIFT) + tid;
        if (v < N) {
            off[v] = s0 + ex;
            dinv[v] = rsqrtf((float)(my + 1));   // +1 self-loop
            if (v == N - 1) off[N] = E;
            // fused gbound (batch sorted)
            int bb = batch[v];
            int prev = (v == 0) ? -1 : batch[v - 1];
            for (int g = prev + 1; g <= bb; ++g) goff[g] = v;
            if (v == N - 1)
                for (int g = bb + 1; g <= G; ++g) goff[g] = N;
        }
    }
    __syncthreads();
    for (int i = s0 + tid; i < s1; i += 256) {
        int p = bkt[i];
        int lo = (p >> 24) & 255;
        int li = atomicAdd(&cur[lo], 1);
        csr[s0 + bas[lo] + li] = p & 0xFFFFFF;
    }
}

// ---------------- skinny GEMM: hs1[N,64](fp16) = (X @ W1) * dinv[row]; row N = zeros ----------------

__global__ __launch_bounds__(256) void k_gemm(const float* __restrict__ X,
                                              const float* __restrict__ W,
                                              const float* __restrict__ dinv,
                                              __half* __restrict__ Y, int N) {
    __shared__ float Ws[64 * 64];
    __shared__ float Xs[16 * 64];
    int tid = threadIdx.x;
#pragma unroll
    for (int i = 0; i < 16; ++i) Ws[tid + 256 * i] = W[tid + 256 * i];

    int row0 = blockIdx.x * 16;
    int r = tid >> 4, c4 = (tid & 15) << 2;
    int row = row0 + r;
    {
        float4 v = make_float4(0.f, 0.f, 0.f, 0.f);
        if (row < N) v = *(const float4*)(X + (size_t)row * DIM + c4);
        *(float4*)(Xs + r * DIM + c4) = v;
    }
    __syncthreads();

    float4 acc = make_float4(0.f, 0.f, 0.f, 0.f);
#pragma unroll
    for (int k = 0; k < 64; ++k) {
        float xk = Xs[r * DIM + k];
        float4 w = *(const float4*)(Ws + k * DIM + c4);
        acc.x += xk * w.x; acc.y += xk * w.y;
        acc.z += xk * w.z; acc.w += xk * w.w;
    }
    if (row < N) {
        float s = dinv[row];
        __half2 p0 = __floats2half2_rn(acc.x * s, acc.y * s);
        __half2 p1 = __floats2half2_rn(acc.z * s, acc.w * s);
        uint2 u;
        u.x = *(unsigned int*)&p0;
        u.y = *(unsigned int*)&p1;
        *(uint2*)(Y + (size_t)row * DIM + c4) = u;
    } else if (row == N) {
        uint2 z; z.x = 0u; z.y = 0u;
        *(uint2*)(Y + (size_t)row * DIM + c4) = z;
    }
}

// ---------------- fused gather (+optional matvec) ----------------
// mode 1 (layer 1): out = ((relu(agg*dv + bias)) @ W2) * dv  as fp16 rows (incl zero row N)
// mode 0 (layer 2): out = agg*dv + bias                      as fp16 rows (pre-relu)
// Each block: 4 waves x 4 nodes; W2 staged to LDS once per block in mode 1.

__global__ __launch_bounds__(256) void k_gather(const __half* __restrict__ hs,
                                                const int* __restrict__ csr_src,
                                                const int* __restrict__ off,
                                                const float* __restrict__ dinv,
                                                const float* __restrict__ bias,
                                                const float* __restrict__ W2,
                                                __half* __restrict__ out,
                                                int N, int fuse) {
    __shared__ float Ws[64 * 64];
    if (fuse) {
#pragma unroll
        for (int i = 0; i < 16; ++i) Ws[threadIdx.x + 256 * i] = W2[threadIdx.x + 256 * i];
        __syncthreads();
        if (blockIdx.x == 0 && threadIdx.x < 32)   // zero row N for next layer's padding
            ((unsigned int*)(out + (size_t)N * DIM))[threadIdx.x] = 0u;
    }

    int wv = threadIdx.x >> 6;
    int lane = threadIdx.x & 63;
    int q = lane >> 4, c = lane & 15;
    const uint2* h2 = (const uint2*)hs;

    for (int it = 0; it < 4; ++it) {
        int v = blockIdx.x * 16 + wv * 4 + it;
        if (v >= N) continue;
        float dv = dinv[v];

        float4 acc = make_float4(0.f, 0.f, 0.f, 0.f);
        if (q == 0) {                      // self-loop term hs[v]
            uint2 u = h2[(size_t)v * 16 + c];
            float2 f0 = __half22float2(*(__half2*)&u.x);
            float2 f1 = __half22float2(*(__half2*)&u.y);
            acc = make_float4(f0.x, f0.y, f1.x, f1.y);
        }

        int k0 = off[v], k1 = off[v + 1];
        for (int kb = k0; kb < k1; kb += 64) {
            int m = k1 - kb;
            int idx = N;                   // zero row for padding lanes
            if (lane < m) idx = csr_src[kb + lane];
            int mlim = m > 64 ? 64 : m;
            int mm = (mlim + 7) & ~7;
            for (int j = 0; j < mm; j += 8) {
                int sA = __shfl(idx, j + q);
                int sB = __shfl(idx, j + 4 + q);
                uint2 uA = h2[(size_t)sA * 16 + c];
                uint2 uB = h2[(size_t)sB * 16 + c];
                float2 a0 = __half22float2(*(__half2*)&uA.x);
                float2 a1 = __half22float2(*(__half2*)&uA.y);
                float2 b0 = __half22float2(*(__half2*)&uB.x);
                float2 b1 = __half22float2(*(__half2*)&uB.y);
                acc.x += a0.x + b0.x; acc.y += a0.y + b0.y;
                acc.z += a1.x + b1.x; acc.w += a1.y + b1.y;
            }
        }
        // reduce quarters -> lanes 0..15 hold float4 agg
        acc.x += __shfl_down(acc.x, 32); acc.y += __shfl_down(acc.y, 32);
        acc.z += __shfl_down(acc.z, 32); acc.w += __shfl_down(acc.w, 32);
        acc.x += __shfl_down(acc.x, 16); acc.y += __shfl_down(acc.y, 16);
        acc.z += __shfl_down(acc.z, 16); acc.w += __shfl_down(acc.w, 16);

        if (!fuse) {
            if (q == 0) {
                float4 bv = ((const float4*)bias)[c];
                __half2 p0 = __floats2half2_rn(acc.x * dv + bv.x, acc.y * dv + bv.y);
                __half2 p1 = __floats2half2_rn(acc.z * dv + bv.z, acc.w * dv + bv.w);
                uint2 u;
                u.x = *(unsigned int*)&p0;
                u.y = *(unsigned int*)&p1;
                ((uint2*)(out + (size_t)v * DIM))[c] = u;
            }
        } else {
            // y = relu(agg*dv + bias) in lanes 0..15 (others garbage, unused by shfl)
            float4 bv = ((const float4*)bias)[c];
            float4 yv;
            yv.x = fmaxf(acc.x * dv + bv.x, 0.f);
            yv.y = fmaxf(acc.y * dv + bv.y, 0.f);
            yv.z = fmaxf(acc.z * dv + bv.z, 0.f);
            yv.w = fmaxf(acc.w * dv + bv.w, 0.f);
            // z[lane] = sum_k y[k] * W2[k][lane]
            float z = 0.f;
#pragma unroll
            for (int k4 = 0; k4 < 16; ++k4) {
                float y0 = __shfl(yv.x, k4);
                float y1 = __shfl(yv.y, k4);
                float y2 = __shfl(yv.z, k4);
                float y3 = __shfl(yv.w, k4);
                z += y0 * Ws[(k4 * 4 + 0) * 64 + lane];
                z += y1 * Ws[(k4 * 4 + 1) * 64 + lane];
                z += y2 * Ws[(k4 * 4 + 2) * 64 + lane];
                z += y3 * Ws[(k4 * 4 + 3) * 64 + lane];
            }
            z *= dv;
            float zo = __shfl_down(z, 1);
            if ((lane & 1) == 0)
                ((__half2*)(out + (size_t)v * DIM))[lane >> 1] = __floats2half2_rn(z, zo);
        }
    }
}

// ---------------- pool: out[g] = mean relu(agg2[v]) (fp16 input) ----------------

__global__ __launch_bounds__(256) void k_pool(const __half* __restrict__ agg,
                                              const int* __restrict__ goff,
                                              float* __restrict__ out, int G) {
    int g = blockIdx.x * 4 + (threadIdx.x >> 6);
    if (g >= G) return;
    int lane = threadIdx.x & 63;
    int q = lane >> 4, c = lane & 15;
    const uint2* h2 = (const uint2*)agg;
    int n0 = goff[g], n1 = goff[g + 1];
    float4 acc = make_float4(0.f, 0.f, 0.f, 0.f);
    for (int i = n0 + q; i < n1; i += 4) {
        uint2 u = h2[(size_t)i * 16 + c];
        float2 f0 = __half22float2(*(__half2*)&u.x);
        float2 f1 = __half22float2(*(__half2*)&u.y);
        acc.x += fmaxf(f0.x, 0.f); acc.y += fmaxf(f0.y, 0.f);
        acc.z += fmaxf(f1.x, 0.f); acc.w += fmaxf(f1.y, 0.f);
    }
    acc.x += __shfl_down(acc.x, 32); acc.y += __shfl_down(acc.y, 32);
    acc.z += __shfl_down(acc.z, 32); acc.w += __shfl_down(acc.w, 32);
    acc.x += __shfl_down(acc.x, 16); acc.y += __shfl_down(acc.y, 16);
    acc.z += __shfl_down(acc.z, 16); acc.w += __shfl_down(acc.w, 16);
    if (q == 0) {
        float inv = 1.0f / fmaxf((float)(n1 - n0), 1.0f);
        *(float4*)(out + ((size_t)g << 6) + (c << 2)) =
            make_float4(acc.x * inv, acc.y * inv, acc.z * inv, acc.w * inv);
    }
}

// ---------------- launch ----------------

static inline int cdiv(int a, int b) { return (a + b - 1) / b; }

extern "C" void kernel_launch(void* const* d_in, const int* in_sizes, int n_in,
                              void* d_out, int out_size, void* d_ws, size_t ws_size,
                              hipStream_t stream) {
    const float* x   = (const float*)d_in[0];
    const float* W1  = (const float*)d_in[1];
    const float* b1  = (const float*)d_in[2];
    const float* W2  = (const float*)d_in[3];
    const float* b2  = (const float*)d_in[4];
    const int*   ei  = (const int*)d_in[5];
    const int*   bat = (const int*)d_in[6];

    const int N = in_sizes[0] / DIM;
    const int E = in_sizes[5] / 2;
    const int G = out_size / DIM;
    const int NB = cdiv(N, BINSZ);           // <= MAXBINS
    const int M  = NB * PB;                  // scan length
    const int* src = ei;
    const int* dst = ei + E;
    float* out = (float*)d_out;

    // workspace: hs1((N+1)*64 h, aliased by bkt then agg2) | hs2((N+1)*64 h) | dinv | off | goff | binoff | C | S | bsums | csr
    __half* hs1    = (__half*)d_ws;                        // (N+1)*64 h
    __half* hs2    = hs1 + (size_t)(N + 1) * DIM;          // (N+1)*64 h
    float*  dinv   = (float*)(hs2 + (size_t)(N + 1) * DIM); // N f
    int*    off    = (int*)(dinv + N);                     // N+1 i
    int*    goff   = off + (N + 1);                        // G+1 i
    int*    binoff = goff + (G + 1);                       // NB+1 i
    int*    C      = binoff + (NB + 1);                    // PB*NB i
    int*    S      = C + (size_t)PB * NB;                  // PB*NB i
    int*    bsums  = S + (size_t)PB * NB;                  // up to 1024 i
    int*    csr    = bsums + 1024;                         // E i
    int*    bkt    = (int*)hs1;                            // E i (aliased, dead before gemm)
    __half* agg2   = hs1;                                  // N*64 h (aliased, hs1 dead after gatherA)

    k_hist<<<PB, 256, 0, stream>>>(dst, C, E, NB);
    int nb2 = cdiv(M, 4096);
    k_scanA<<<nb2, 1024, 0, stream>>>(C, S, bsums, NB, M);
    k_scanB<<<1, 1024, 0, stream>>>(bsums, nb2);
    k_scanC<<<nb2, 1024, 0, stream>>>(S, bsums, binoff, NB, M, E);
    k_bucket<<<PB, 256, 0, stream>>>(src, dst, S, bkt, E, NB);
    k_binsort<<<NB, 256, 0, stream>>>(bkt, binoff, csr, off, dinv, bat, goff, N, G, E);

    k_gemm<<<cdiv(N + 1, 16), 256, 0, stream>>>(x, W1, dinv, hs1, N);
    // layer 1 gather fused with layer-2 transform: hs2 = (relu(agg1) @ W2) * dinv
    k_gather<<<cdiv(N, 16), 256, 0, stream>>>(hs1, csr, off, dinv, b1, W2, hs2, N, 1);
    // layer 2 gather: agg2 = agg*dv + b2 (pre-relu, fp16)
    k_gather<<<cdiv(N, 16), 256, 0, stream>>>(hs2, csr, off, dinv, b2, W2, agg2, N, 0);

    k_pool<<<cdiv(G, 4), 256, 0, stream>>>(agg2, goff, out, G);
}

// Round 12
// 278.889 us; speedup vs baseline: 1.2112x; 1.2112x over previous
//
#include <hip/hip_runtime.h>
#include <hip/hip_fp16.h>

#define DIM 64
#define BIN_SHIFT 8
#define BINSZ 256      // nodes per bin
#define MAXBINS 512    // supports N up to 131072
#define PB 256         // edge-slice blocks for hist/bucket (power of 2)
#define PB_LOG 8

// ---------------- pass 1: per-block LDS histogram -> C[blk][bin] ----------------

__global__ __launch_bounds__(256) void k_hist(const int* __restrict__ dst,
                                              int* __restrict__ C, int E, int NB) {
    __shared__ int h[MAXBINS];
    for (int i = threadIdx.x; i < NB; i += 256) h[i] = 0;
    __syncthreads();
    int per = (E + PB - 1) / PB;
    int e0 = blockIdx.x * per;
    int e1 = e0 + per; if (e1 > E) e1 = E;
    for (int e = e0 + (int)threadIdx.x; e < e1; e += 256)
        atomicAdd(&h[dst[e] >> BIN_SHIFT], 1);
    __syncthreads();
    for (int i = threadIdx.x; i < NB; i += 256)
        C[blockIdx.x * NB + i] = h[i];
}

// ---------------- pass 2: exclusive scan of C in bin-major logical order ----------------

__global__ __launch_bounds__(1024) void k_scanA(const int* __restrict__ C,
                                                int* __restrict__ S,
                                                int* __restrict__ bsums, int NB, int M) {
    __shared__ int sh[1024];
    int tid = threadIdx.x;
    int j0 = blockIdx.x * 4096 + tid * 4;
    int v[4]; int sum = 0;
#pragma unroll
    for (int t = 0; t < 4; ++t) {
        int j = j0 + t; int x = 0;
        if (j < M) { int bin = j >> PB_LOG, blk = j & (PB - 1); x = C[blk * NB + bin]; }
        v[t] = sum; sum += x;
    }
    sh[tid] = sum;
    __syncthreads();
#pragma unroll
    for (int d = 1; d < 1024; d <<= 1) {
        int t = (tid >= d) ? sh[tid - d] : 0;
        __syncthreads();
        sh[tid] += t;
        __syncthreads();
    }
    int excl = sh[tid] - sum;
#pragma unroll
    for (int t = 0; t < 4; ++t) {
        int j = j0 + t;
        if (j < M) S[j] = excl + v[t];
    }
    if (tid == 1023) bsums[blockIdx.x] = sh[1023];
}

__global__ __launch_bounds__(1024) void k_scanB(int* __restrict__ bsums, int nb) {
    __shared__ int s[1024];
    int tid = threadIdx.x;
    int v = (tid < nb) ? bsums[tid] : 0;
    s[tid] = v;
    __syncthreads();
#pragma unroll
    for (int d = 1; d < 1024; d <<= 1) {
        int t = (tid >= d) ? s[tid - d] : 0;
        __syncthreads();
        s[tid] += t;
        __syncthreads();
    }
    if (tid < nb) bsums[tid] = s[tid] - v;
}

__global__ __launch_bounds__(1024) void k_scanC(int* __restrict__ S,
                                                const int* __restrict__ bsums,
                                                int* __restrict__ binoff,
                                                int NB, int M, int E) {
    int tid = threadIdx.x;
    int j0 = blockIdx.x * 4096 + tid * 4;
    int add = bsums[blockIdx.x];
#pragma unroll
    for (int t = 0; t < 4; ++t) {
        int j = j0 + t;
        if (j < M) {
            int val = S[j] + add;
            S[j] = val;
            if ((j & (PB - 1)) == 0) binoff[j >> PB_LOG] = val;
        }
    }
    if (blockIdx.x == 0 && tid == 0) binoff[NB] = E;
}

// ---------------- pass 3: one-pass bucket scatter, LDS cursors ----------------

__global__ __launch_bounds__(256) void k_bucket(const int* __restrict__ src,
                                                const int* __restrict__ dst,
                                                const int* __restrict__ S,
                                                int* __restrict__ bkt, int E, int NB) {
    __shared__ int lcur[MAXBINS];
    int blk = blockIdx.x;
    for (int i = threadIdx.x; i < NB; i += 256)
        lcur[i] = S[i * PB + blk];
    __syncthreads();
    int per = (E + PB - 1) / PB;
    int e0 = blk * per;
    int e1 = e0 + per; if (e1 > E) e1 = E;
    for (int e = e0 + (int)threadIdx.x; e < e1; e += 256) {
        int d = dst[e];
        int pos = atomicAdd(&lcur[d >> BIN_SHIFT], 1);
        bkt[pos] = src[e] | ((d & (BINSZ - 1)) << 24);
    }
}

// ---------------- pass 4: per-bin counting sort -> csr, off, dinv; + gbound fused ----------------

__global__ __launch_bounds__(256) void k_binsort(const int* __restrict__ bkt,
                                                 const int* __restrict__ binoff,
                                                 int* __restrict__ csr,
                                                 int* __restrict__ off,
                                                 float* __restrict__ dinv,
                                                 const int* __restrict__ batch,
                                                 int* __restrict__ goff,
                                                 int N, int G, int E) {
    __shared__ int cnt[BINSZ], bas[BINSZ], cur[BINSZ];
    int tid = threadIdx.x;
    int b = blockIdx.x;
    int s0 = binoff[b], s1 = binoff[b + 1];
    cnt[tid] = 0; cur[tid] = 0;
    __syncthreads();
    for (int i = s0 + tid; i < s1; i += 256)
        atomicAdd(&cnt[(bkt[i] >> 24) & 255], 1);
    __syncthreads();
    int my = cnt[tid];
    bas[tid] = my;
    __syncthreads();
#pragma unroll
    for (int d = 1; d < 256; d <<= 1) {
        int t = (tid >= d) ? bas[tid - d] : 0;
        __syncthreads();
        bas[tid] += t;
        __syncthreads();
    }
    int ex = bas[tid] - my;
    __syncthreads();
    bas[tid] = ex;
    {
        int v = (b << BIN_SHIFT) + tid;
        if (v < N) {
            off[v] = s0 + ex;
            dinv[v] = rsqrtf((float)(my + 1));   // +1 self-loop
            if (v == N - 1) off[N] = E;
            // fused gbound (batch sorted)
            int bb = batch[v];
            int prev = (v == 0) ? -1 : batch[v - 1];
            for (int g = prev + 1; g <= bb; ++g) goff[g] = v;
            if (v == N - 1)
                for (int g = bb + 1; g <= G; ++g) goff[g] = N;
        }
    }
    __syncthreads();
    for (int i = s0 + tid; i < s1; i += 256) {
        int p = bkt[i];
        int lo = (p >> 24) & 255;
        int li = atomicAdd(&cur[lo], 1);
        csr[s0 + bas[lo] + li] = p & 0xFFFFFF;
    }
}

// ---------------- skinny GEMM: hs[row] = (act(X[row]) @ W) * dinv[row] (fp16 out) ----------------
// layer 1: Xf (fp32), no relu. layer 2: Xh (fp16 agg, pre-relu) -> relu applied here.
// row N written as zeros (gather padding row).

__global__ __launch_bounds__(256) void k_gemm(const float* __restrict__ Xf,
                                              const __half* __restrict__ Xh,
                                              const float* __restrict__ W,
                                              const float* __restrict__ dinv,
                                              __half* __restrict__ Y, int N, int relu_in) {
    __shared__ float Ws[64 * 64];
    __shared__ float Xs[16 * 64];
    int tid = threadIdx.x;
#pragma unroll
    for (int i = 0; i < 16; ++i) Ws[tid + 256 * i] = W[tid + 256 * i];

    int row0 = blockIdx.x * 16;
    int r = tid >> 4, c4 = (tid & 15) << 2;
    int row = row0 + r;
    {
        float4 v = make_float4(0.f, 0.f, 0.f, 0.f);
        if (row < N) {
            if (Xh) {
                uint2 u = *(const uint2*)(Xh + (size_t)row * DIM + c4);
                float2 f0 = __half22float2(*(__half2*)&u.x);
                float2 f1 = __half22float2(*(__half2*)&u.y);
                v = make_float4(f0.x, f0.y, f1.x, f1.y);
            } else {
                v = *(const float4*)(Xf + (size_t)row * DIM + c4);
            }
            if (relu_in) {
                v.x = fmaxf(v.x, 0.f); v.y = fmaxf(v.y, 0.f);
                v.z = fmaxf(v.z, 0.f); v.w = fmaxf(v.w, 0.f);
            }
        }
        *(float4*)(Xs + r * DIM + c4) = v;
    }
    __syncthreads();

    float4 acc = make_float4(0.f, 0.f, 0.f, 0.f);
#pragma unroll
    for (int k = 0; k < 64; ++k) {
        float xk = Xs[r * DIM + k];
        float4 w = *(const float4*)(Ws + k * DIM + c4);
        acc.x += xk * w.x; acc.y += xk * w.y;
        acc.z += xk * w.z; acc.w += xk * w.w;
    }
    if (row < N) {
        float s = dinv[row];
        __half2 p0 = __floats2half2_rn(acc.x * s, acc.y * s);
        __half2 p1 = __floats2half2_rn(acc.z * s, acc.w * s);
        uint2 u;
        u.x = *(unsigned int*)&p0;
        u.y = *(unsigned int*)&p1;
        *(uint2*)(Y + (size_t)row * DIM + c4) = u;
    } else if (row == N) {
        uint2 z; z.x = 0u; z.y = 0u;
        *(uint2*)(Y + (size_t)row * DIM + c4) = z;
    }
}

// ---------------- gather: agg[v] = dv*(hs[v] + sum hs[nbr]) + bias (fp16 out, pre-relu) ----------------
// one 64-lane wave per node (TLP is the lifeblood here — do not batch nodes per wave)

__global__ __launch_bounds__(256) void k_gather(const __half* __restrict__ hs,
                                                const int* __restrict__ csr_src,
                                                const int* __restrict__ off,
                                                const float* __restrict__ dinv,
                                                const float* __restrict__ bias,
                                                __half* __restrict__ agg, int N) {
    int v = (blockIdx.x * 256 + threadIdx.x) >> 6;
    int lane = threadIdx.x & 63;
    if (v >= N) return;
    int q = lane >> 4, c = lane & 15;
    const uint2* h2 = (const uint2*)hs;

    float4 acc = make_float4(0.f, 0.f, 0.f, 0.f);
    if (q == 0) {                          // self-loop term hs[v]
        uint2 u = h2[(size_t)v * 16 + c];
        float2 f0 = __half22float2(*(__half2*)&u.x);
        float2 f1 = __half22float2(*(__half2*)&u.y);
        acc = make_float4(f0.x, f0.y, f1.x, f1.y);
    }

    int k0 = off[v], k1 = off[v + 1];
    for (int kb = k0; kb < k1; kb += 64) {
        int m = k1 - kb;
        int idx = N;                       // zero row for padding lanes
        if (lane < m) idx = csr_src[kb + lane];
        int mlim = m > 64 ? 64 : m;
        int mm = (mlim + 7) & ~7;
        for (int j = 0; j < mm; j += 8) {  // 8 edges per iter: 2 8B gathers/lane
            int sA = __shfl(idx, j + q);
            int sB = __shfl(idx, j + 4 + q);
            uint2 uA = h2[(size_t)sA * 16 + c];
            uint2 uB = h2[(size_t)sB * 16 + c];
            float2 a0 = __half22float2(*(__half2*)&uA.x);
            float2 a1 = __half22float2(*(__half2*)&uA.y);
            float2 b0 = __half22float2(*(__half2*)&uB.x);
            float2 b1 = __half22float2(*(__half2*)&uB.y);
            acc.x += a0.x + b0.x; acc.y += a0.y + b0.y;
            acc.z += a1.x + b1.x; acc.w += a1.y + b1.y;
        }
    }
    // reduce quarters: lanes (c, c+16, c+32, c+48) -> lane c
    acc.x += __shfl_down(acc.x, 32); acc.y += __shfl_down(acc.y, 32);
    acc.z += __shfl_down(acc.z, 32); acc.w += __shfl_down(acc.w, 32);
    acc.x += __shfl_down(acc.x, 16); acc.y += __shfl_down(acc.y, 16);
    acc.z += __shfl_down(acc.z, 16); acc.w += __shfl_down(acc.w, 16);
    if (q == 0) {
        float dv = dinv[v];
        float4 bv = ((const float4*)bias)[c];
        __half2 p0 = __floats2half2_rn(acc.x * dv + bv.x, acc.y * dv + bv.y);
        __half2 p1 = __floats2half2_rn(acc.z * dv + bv.z, acc.w * dv + bv.w);
        uint2 u;
        u.x = *(unsigned int*)&p0;
        u.y = *(unsigned int*)&p1;
        ((uint2*)(agg + (size_t)v * DIM))[c] = u;
    }
}

// ---------------- pool: out[g] = mean relu(agg2[v]) (fp16 input) ----------------

__global__ __launch_bounds__(256) void k_pool(const __half* __restrict__ agg,
                                              const int* __restrict__ goff,
                                              float* __restrict__ out, int G) {
    int g = blockIdx.x * 4 + (threadIdx.x >> 6);
    if (g >= G) return;
    int lane = threadIdx.x & 63;
    int q = lane >> 4, c = lane & 15;
    const uint2* h2 = (const uint2*)agg;
    int n0 = goff[g], n1 = goff[g + 1];
    float4 acc = make_float4(0.f, 0.f, 0.f, 0.f);
    for (int i = n0 + q; i < n1; i += 4) {
        uint2 u = h2[(size_t)i * 16 + c];
        float2 f0 = __half22float2(*(__half2*)&u.x);
        float2 f1 = __half22float2(*(__half2*)&u.y);
        acc.x += fmaxf(f0.x, 0.f); acc.y += fmaxf(f0.y, 0.f);
        acc.z += fmaxf(f1.x, 0.f); acc.w += fmaxf(f1.y, 0.f);
    }
    acc.x += __shfl_down(acc.x, 32); acc.y += __shfl_down(acc.y, 32);
    acc.z += __shfl_down(acc.z, 32); acc.w += __shfl_down(acc.w, 32);
    acc.x += __shfl_down(acc.x, 16); acc.y += __shfl_down(acc.y, 16);
    acc.z += __shfl_down(acc.z, 16); acc.w += __shfl_down(acc.w, 16);
    if (q == 0) {
        float inv = 1.0f / fmaxf((float)(n1 - n0), 1.0f);
        *(float4*)(out + ((size_t)g << 6) + (c << 2)) =
            make_float4(acc.x * inv, acc.y * inv, acc.z * inv, acc.w * inv);
    }
}

// ---------------- launch ----------------

static inline int cdiv(int a, int b) { return (a + b - 1) / b; }

extern "C" void kernel_launch(void* const* d_in, const int* in_sizes, int n_in,
                              void* d_out, int out_size, void* d_ws, size_t ws_size,
                              hipStream_t stream) {
    const float* x   = (const float*)d_in[0];
    const float* W1  = (const float*)d_in[1];
    const float* b1  = (const float*)d_in[2];
    const float* W2  = (const float*)d_in[3];
    const float* b2  = (const float*)d_in[4];
    const int*   ei  = (const int*)d_in[5];
    const int*   bat = (const int*)d_in[6];

    const int N = in_sizes[0] / DIM;
    const int E = in_sizes[5] / 2;
    const int G = out_size / DIM;
    const int NB = cdiv(N, BINSZ);           // <= MAXBINS
    const int M  = NB * PB;                  // scan length
    const int* src = ei;
    const int* dst = ei + E;
    float* out = (float*)d_out;

    // workspace: hs1 | hs2 | agg1 | dinv | off | goff | binoff | C | S | bsums | csr
    // bkt aliases hs1 (dead before gemm1); agg2 aliases hs1 (dead after gather1).
    __half* hs1    = (__half*)d_ws;                         // (N+1)*64 h
    __half* hs2    = hs1 + (size_t)(N + 1) * DIM;           // (N+1)*64 h
    __half* agg1   = hs2 + (size_t)(N + 1) * DIM;           // N*64 h
    float*  dinv   = (float*)(agg1 + (size_t)N * DIM);      // N f
    int*    off    = (int*)(dinv + N);                      // N+1 i
    int*    goff   = off + (N + 1);                         // G+1 i
    int*    binoff = goff + (G + 1);                        // NB+1 i
    int*    C      = binoff + (NB + 1);                     // PB*NB i
    int*    S      = C + (size_t)PB * NB;                   // PB*NB i
    int*    bsums  = S + (size_t)PB * NB;                   // up to 1024 i
    int*    csr    = bsums + 1024;                          // E i
    int*    bkt    = (int*)hs1;                             // E i (aliased)
    __half* agg2   = hs1;                                   // N*64 h (aliased)

    k_hist<<<PB, 256, 0, stream>>>(dst, C, E, NB);
    int nb2 = cdiv(M, 4096);
    k_scanA<<<nb2, 1024, 0, stream>>>(C, S, bsums, NB, M);
    k_scanB<<<1, 1024, 0, stream>>>(bsums, nb2);
    k_scanC<<<nb2, 1024, 0, stream>>>(S, bsums, binoff, NB, M, E);
    k_bucket<<<PB, 256, 0, stream>>>(src, dst, S, bkt, E, NB);
    k_binsort<<<NB, 256, 0, stream>>>(bkt, binoff, csr, off, dinv, bat, goff, N, G, E);

    // layer 1: hs1 = (x @ W1) * dinv ; agg1 = gather(hs1) + b1 (fp16, pre-relu)
    k_gemm<<<cdiv(N + 1, 16), 256, 0, stream>>>(x, nullptr, W1, dinv, hs1, N, 0);
    k_gather<<<cdiv(N, 4), 256, 0, stream>>>(hs1, csr, off, dinv, b1, agg1, N);

    // layer 2: hs2 = (relu(agg1) @ W2) * dinv ; agg2 = gather(hs2) + b2 (fp16, pre-relu)
    k_gemm<<<cdiv(N + 1, 16), 256, 0, stream>>>(nullptr, agg1, W2, dinv, hs2, N, 1);
    k_gather<<<cdiv(N, 4), 256, 0, stream>>>(hs2, csr, off, dinv, b2, agg2, N);

    k_pool<<<cdiv(G, 4), 256, 0, stream>>>(agg2, goff, out, G);
}

// Round 13
// 269.359 us; speedup vs baseline: 1.2541x; 1.0354x over previous
//
#include <hip/hip_runtime.h>
#include <hip/hip_fp16.h>

#define DIM 64
#define BIN_SHIFT 8
#define BINSZ 256      // nodes per bin
#define MAXBINS 512    // supports N up to 131072
#define PB 256         // edge-slice blocks for hist/bucket (power of 2)
#define PB_LOG 8

// ---------------- pass 1: per-block LDS histogram -> C[blk][bin] ----------------

__global__ __launch_bounds__(256) void k_hist(const int* __restrict__ dst,
                                              int* __restrict__ C, int E, int NB) {
    __shared__ int h[MAXBINS];
    for (int i = threadIdx.x; i < NB; i += 256) h[i] = 0;
    __syncthreads();
    int per = (E + PB - 1) / PB;
    int e0 = blockIdx.x * per;
    int e1 = e0 + per; if (e1 > E) e1 = E;
    for (int e = e0 + (int)threadIdx.x; e < e1; e += 256)
        atomicAdd(&h[dst[e] >> BIN_SHIFT], 1);
    __syncthreads();
    for (int i = threadIdx.x; i < NB; i += 256)
        C[blockIdx.x * NB + i] = h[i];
}

// ---------------- pass 2a: chunk-local exclusive scan of C (bin-major order) ----------------
// logical j: bin = j>>PB_LOG, blk = j&(PB-1); S[j] = chunk-local start; bsums[chunk] = chunk total.
// Consumers add bsums[j>>12] inline (scanC eliminated).

__global__ __launch_bounds__(1024) void k_scanA(const int* __restrict__ C,
                                                int* __restrict__ S,
                                                int* __restrict__ bsums, int NB, int M) {
    __shared__ int sh[1024];
    int tid = threadIdx.x;
    int j0 = blockIdx.x * 4096 + tid * 4;
    int v[4]; int sum = 0;
#pragma unroll
    for (int t = 0; t < 4; ++t) {
        int j = j0 + t; int x = 0;
        if (j < M) { int bin = j >> PB_LOG, blk = j & (PB - 1); x = C[blk * NB + bin]; }
        v[t] = sum; sum += x;
    }
    sh[tid] = sum;
    __syncthreads();
#pragma unroll
    for (int d = 1; d < 1024; d <<= 1) {
        int t = (tid >= d) ? sh[tid - d] : 0;
        __syncthreads();
        sh[tid] += t;
        __syncthreads();
    }
    int excl = sh[tid] - sum;
#pragma unroll
    for (int t = 0; t < 4; ++t) {
        int j = j0 + t;
        if (j < M) S[j] = excl + v[t];
    }
    if (tid == 1023) bsums[blockIdx.x] = sh[1023];
}

// ---------------- pass 2b: exclusive scan of chunk sums ----------------

__global__ __launch_bounds__(1024) void k_scanB(int* __restrict__ bsums, int nb) {
    __shared__ int s[1024];
    int tid = threadIdx.x;
    int v = (tid < nb) ? bsums[tid] : 0;
    s[tid] = v;
    __syncthreads();
#pragma unroll
    for (int d = 1; d < 1024; d <<= 1) {
        int t = (tid >= d) ? s[tid - d] : 0;
        __syncthreads();
        s[tid] += t;
        __syncthreads();
    }
    if (tid < nb) bsums[tid] = s[tid] - v;
}

// ---------------- pass 3: one-pass bucket scatter, LDS cursors ----------------

__global__ __launch_bounds__(256) void k_bucket(const int* __restrict__ src,
                                                const int* __restrict__ dst,
                                                const int* __restrict__ S,
                                                const int* __restrict__ bsums,
                                                int* __restrict__ bkt, int E, int NB) {
    __shared__ int lcur[MAXBINS];
    int blk = blockIdx.x;
    for (int i = threadIdx.x; i < NB; i += 256) {
        int j = i * PB + blk;
        lcur[i] = S[j] + bsums[j >> 12];
    }
    __syncthreads();
    int per = (E + PB - 1) / PB;
    int e0 = blk * per;
    int e1 = e0 + per; if (e1 > E) e1 = E;
    for (int e = e0 + (int)threadIdx.x; e < e1; e += 256) {
        int d = dst[e];
        int pos = atomicAdd(&lcur[d >> BIN_SHIFT], 1);
        bkt[pos] = src[e] | ((d & (BINSZ - 1)) << 24);
    }
}

// ---------------- pass 4: per-bin counting sort (shfl scan) -> csr, off, dinv; + gbound ----------------

__global__ __launch_bounds__(256) void k_binsort(const int* __restrict__ bkt,
                                                 const int* __restrict__ S,
                                                 const int* __restrict__ bsums,
                                                 int* __restrict__ csr,
                                                 int* __restrict__ off,
                                                 float* __restrict__ dinv,
                                                 const int* __restrict__ batch,
                                                 int* __restrict__ goff,
                                                 int N, int G, int E, int NB) {
    __shared__ int cnt[BINSZ], bas[BINSZ], cur[BINSZ];
    __shared__ int wsum[4];
    int tid = threadIdx.x;
    int b = blockIdx.x;
    int j0 = b << PB_LOG;
    int s0 = S[j0] + bsums[j0 >> 12];
    int s1 = E;
    if (b + 1 < NB) { int j1 = (b + 1) << PB_LOG; s1 = S[j1] + bsums[j1 >> 12]; }
    cnt[tid] = 0; cur[tid] = 0;
    __syncthreads();
    for (int i = s0 + tid; i < s1; i += 256)
        atomicAdd(&cnt[(bkt[i] >> 24) & 255], 1);
    __syncthreads();
    int my = cnt[tid];
    // wave-level inclusive scan + cross-wave fixup (replaces 256-step LDS scan)
    int lane = tid & 63, wv = tid >> 6;
    int x = my;
#pragma unroll
    for (int d = 1; d < 64; d <<= 1) {
        int t = __shfl_up(x, d);
        if (lane >= d) x += t;
    }
    if (lane == 63) wsum[wv] = x;
    __syncthreads();
    int prefix = 0;
    for (int w = 0; w < wv; ++w) prefix += wsum[w];
    int ex = x + prefix - my;               // exclusive base within bin
    bas[tid] = ex;
    {
        int v = (b << BIN_SHIFT) + tid;
        if (v < N) {
            off[v] = s0 + ex;
            dinv[v] = rsqrtf((float)(my + 1));   // +1 self-loop
            if (v == N - 1) off[N] = E;
            // fused gbound (batch sorted)
            int bb = batch[v];
            int prev = (v == 0) ? -1 : batch[v - 1];
            for (int g = prev + 1; g <= bb; ++g) goff[g] = v;
            if (v == N - 1)
                for (int g = bb + 1; g <= G; ++g) goff[g] = N;
        }
    }
    __syncthreads();
    for (int i = s0 + tid; i < s1; i += 256) {
        int p = bkt[i];
        int lo = (p >> 24) & 255;
        int li = atomicAdd(&cur[lo], 1);
        csr[s0 + bas[lo] + li] = p & 0xFFFFFF;
    }
}

// ---------------- skinny GEMM: hs[row] = (act(X[row]) @ W) * dinv[row] (fp16 out) ----------------

__global__ __launch_bounds__(256) void k_gemm(const float* __restrict__ Xf,
                                              const __half* __restrict__ Xh,
                                              const float* __restrict__ W,
                                              const float* __restrict__ dinv,
                                              __half* __restrict__ Y, int N, int relu_in) {
    __shared__ float Ws[64 * 64];
    __shared__ float Xs[16 * 64];
    int tid = threadIdx.x;
#pragma unroll
    for (int i = 0; i < 16; ++i) Ws[tid + 256 * i] = W[tid + 256 * i];

    int row0 = blockIdx.x * 16;
    int r = tid >> 4, c4 = (tid & 15) << 2;
    int row = row0 + r;
    {
        float4 v = make_float4(0.f, 0.f, 0.f, 0.f);
        if (row < N) {
            if (Xh) {
                uint2 u = *(const uint2*)(Xh + (size_t)row * DIM + c4);
                float2 f0 = __half22float2(*(__half2*)&u.x);
                float2 f1 = __half22float2(*(__half2*)&u.y);
                v = make_float4(f0.x, f0.y, f1.x, f1.y);
            } else {
                v = *(const float4*)(Xf + (size_t)row * DIM + c4);
            }
            if (relu_in) {
                v.x = fmaxf(v.x, 0.f); v.y = fmaxf(v.y, 0.f);
                v.z = fmaxf(v.z, 0.f); v.w = fmaxf(v.w, 0.f);
            }
        }
        *(float4*)(Xs + r * DIM + c4) = v;
    }
    __syncthreads();

    float4 acc = make_float4(0.f, 0.f, 0.f, 0.f);
#pragma unroll
    for (int k = 0; k < 64; ++k) {
        float xk = Xs[r * DIM + k];
        float4 w = *(const float4*)(Ws + k * DIM + c4);
        acc.x += xk * w.x; acc.y += xk * w.y;
        acc.z += xk * w.z; acc.w += xk * w.w;
    }
    if (row < N) {
        float s = dinv[row];
        __half2 p0 = __floats2half2_rn(acc.x * s, acc.y * s);
        __half2 p1 = __floats2half2_rn(acc.z * s, acc.w * s);
        uint2 u;
        u.x = *(unsigned int*)&p0;
        u.y = *(unsigned int*)&p1;
        *(uint2*)(Y + (size_t)row * DIM + c4) = u;
    } else if (row == N) {
        uint2 z; z.x = 0u; z.y = 0u;
        *(uint2*)(Y + (size_t)row * DIM + c4) = z;
    }
}

// ---------------- gather: agg[v] = dv*(hs[v] + sum hs[nbr]) + bias (fp16 out, pre-relu) ----------------
// one 64-lane wave per node; 16 edges/iter with 4 loads in flight, split accumulators

__global__ __launch_bounds__(256) void k_gather(const __half* __restrict__ hs,
                                                const int* __restrict__ csr_src,
                                                const int* __restrict__ off,
                                                const float* __restrict__ dinv,
                                                const float* __restrict__ bias,
                                                __half* __restrict__ agg, int N) {
    int v = (blockIdx.x * 256 + threadIdx.x) >> 6;
    int lane = threadIdx.x & 63;
    if (v >= N) return;
    int q = lane >> 4, c = lane & 15;
    const uint2* h2 = (const uint2*)hs;

    float4 accA = make_float4(0.f, 0.f, 0.f, 0.f);
    float4 accB = make_float4(0.f, 0.f, 0.f, 0.f);
    if (q == 0) {                          // self-loop term hs[v]
        uint2 u = h2[(size_t)v * 16 + c];
        float2 f0 = __half22float2(*(__half2*)&u.x);
        float2 f1 = __half22float2(*(__half2*)&u.y);
        accA = make_float4(f0.x, f0.y, f1.x, f1.y);
    }

    int k0 = off[v], k1 = off[v + 1];
    for (int kb = k0; kb < k1; kb += 64) {
        int m = k1 - kb;
        int idx = N;                       // zero row for padding lanes
        if (lane < m) idx = csr_src[kb + lane];
        int mlim = m > 64 ? 64 : m;
        int mm = (mlim + 15) & ~15;
        for (int j = 0; j < mm; j += 16) { // 16 edges per iter: 4 8B gathers in flight
            int sA = __shfl(idx, j + q);
            int sB = __shfl(idx, j + 4 + q);
            int sC = __shfl(idx, j + 8 + q);
            int sD = __shfl(idx, j + 12 + q);
            uint2 uA = h2[(size_t)sA * 16 + c];
            uint2 uB = h2[(size_t)sB * 16 + c];
            uint2 uC = h2[(size_t)sC * 16 + c];
            uint2 uD = h2[(size_t)sD * 16 + c];
            float2 a0 = __half22float2(*(__half2*)&uA.x);
            float2 a1 = __half22float2(*(__half2*)&uA.y);
            float2 b0 = __half22float2(*(__half2*)&uB.x);
            float2 b1 = __half22float2(*(__half2*)&uB.y);
            float2 c0 = __half22float2(*(__half2*)&uC.x);
            float2 c1 = __half22float2(*(__half2*)&uC.y);
            float2 d0 = __half22float2(*(__half2*)&uD.x);
            float2 d1 = __half22float2(*(__half2*)&uD.y);
            accA.x += a0.x + b0.x; accA.y += a0.y + b0.y;
            accA.z += a1.x + b1.x; accA.w += a1.y + b1.y;
            accB.x += c0.x + d0.x; accB.y += c0.y + d0.y;
            accB.z += c1.x + d1.x; accB.w += c1.y + d1.y;
        }
    }
    float4 acc = make_float4(accA.x + accB.x, accA.y + accB.y,
                             accA.z + accB.z, accA.w + accB.w);
    // reduce quarters: lanes (c, c+16, c+32, c+48) -> lane c
    acc.x += __shfl_down(acc.x, 32); acc.y += __shfl_down(acc.y, 32);
    acc.z += __shfl_down(acc.z, 32); acc.w += __shfl_down(acc.w, 32);
    acc.x += __shfl_down(acc.x, 16); acc.y += __shfl_down(acc.y, 16);
    acc.z += __shfl_down(acc.z, 16); acc.w += __shfl_down(acc.w, 16);
    if (q == 0) {
        float dv = dinv[v];
        float4 bv = ((const float4*)bias)[c];
        __half2 p0 = __floats2half2_rn(acc.x * dv + bv.x, acc.y * dv + bv.y);
        __half2 p1 = __floats2half2_rn(acc.z * dv + bv.z, acc.w * dv + bv.w);
        uint2 u;
        u.x = *(unsigned int*)&p0;
        u.y = *(unsigned int*)&p1;
        ((uint2*)(agg + (size_t)v * DIM))[c] = u;
    }
}

// ---------------- pool: out[g] = mean relu(agg2[v]) (fp16 input) ----------------

__global__ __launch_bounds__(256) void k_pool(const __half* __restrict__ agg,
                                              const int* __restrict__ goff,
                                              float* __restrict__ out, int G) {
    int g = blockIdx.x * 4 + (threadIdx.x >> 6);
    if (g >= G) return;
    int lane = threadIdx.x & 63;
    int q = lane >> 4, c = lane & 15;
    const uint2* h2 = (const uint2*)agg;
    int n0 = goff[g], n1 = goff[g + 1];
    float4 acc = make_float4(0.f, 0.f, 0.f, 0.f);
    for (int i = n0 + q; i < n1; i += 4) {
        uint2 u = h2[(size_t)i * 16 + c];
        float2 f0 = __half22float2(*(__half2*)&u.x);
        float2 f1 = __half22float2(*(__half2*)&u.y);
        acc.x += fmaxf(f0.x, 0.f); acc.y += fmaxf(f0.y, 0.f);
        acc.z += fmaxf(f1.x, 0.f); acc.w += fmaxf(f1.y, 0.f);
    }
    acc.x += __shfl_down(acc.x, 32); acc.y += __shfl_down(acc.y, 32);
    acc.z += __shfl_down(acc.z, 32); acc.w += __shfl_down(acc.w, 32);
    acc.x += __shfl_down(acc.x, 16); acc.y += __shfl_down(acc.y, 16);
    acc.z += __shfl_down(acc.z, 16); acc.w += __shfl_down(acc.w, 16);
    if (q == 0) {
        float inv = 1.0f / fmaxf((float)(n1 - n0), 1.0f);
        *(float4*)(out + ((size_t)g << 6) + (c << 2)) =
            make_float4(acc.x * inv, acc.y * inv, acc.z * inv, acc.w * inv);
    }
}

// ---------------- launch ----------------

static inline int cdiv(int a, int b) { return (a + b - 1) / b; }

extern "C" void kernel_launch(void* const* d_in, const int* in_sizes, int n_in,
                              void* d_out, int out_size, void* d_ws, size_t ws_size,
                              hipStream_t stream) {
    const float* x   = (const float*)d_in[0];
    const float* W1  = (const float*)d_in[1];
    const float* b1  = (const float*)d_in[2];
    const float* W2  = (const float*)d_in[3];
    const float* b2  = (const float*)d_in[4];
    const int*   ei  = (const int*)d_in[5];
    const int*   bat = (const int*)d_in[6];

    const int N = in_sizes[0] / DIM;
    const int E = in_sizes[5] / 2;
    const int G = out_size / DIM;
    const int NB = cdiv(N, BINSZ);           // <= MAXBINS
    const int M  = NB * PB;                  // scan length
    const int* src = ei;
    const int* dst = ei + E;
    float* out = (float*)d_out;

    // workspace: hs1 | hs2 | agg1 | dinv | off | goff | C | S | bsums | csr
    // bkt aliases hs1 (dead before gemm1); agg2 aliases hs1 (dead after gather1).
    __half* hs1    = (__half*)d_ws;                         // (N+1)*64 h
    __half* hs2    = hs1 + (size_t)(N + 1) * DIM;           // (N+1)*64 h
    __half* agg1   = hs2 + (size_t)(N + 1) * DIM;           // N*64 h
    float*  dinv   = (float*)(agg1 + (size_t)N * DIM);      // N f
    int*    off    = (int*)(dinv + N);                      // N+1 i
    int*    goff   = off + (N + 1);                         // G+1 i
    int*    C      = goff + (G + 1);                        // PB*NB i
    int*    S      = C + (size_t)PB * NB;                   // PB*NB i
    int*    bsums  = S + (size_t)PB * NB;                   // up to 1024 i
    int*    csr    = bsums + 1024;                          // E i
    int*    bkt    = (int*)hs1;                             // E i (aliased)
    __half* agg2   = hs1;                                   // N*64 h (aliased)

    k_hist<<<PB, 256, 0, stream>>>(dst, C, E, NB);
    int nb2 = cdiv(M, 4096);
    k_scanA<<<nb2, 1024, 0, stream>>>(C, S, bsums, NB, M);
    k_scanB<<<1, 1024, 0, stream>>>(bsums, nb2);
    k_bucket<<<PB, 256, 0, stream>>>(src, dst, S, bsums, bkt, E, NB);
    k_binsort<<<NB, 256, 0, stream>>>(bkt, S, bsums, csr, off, dinv, bat, goff, N, G, E, NB);

    // layer 1: hs1 = (x @ W1) * dinv ; agg1 = gather(hs1) + b1 (fp16, pre-relu)
    k_gemm<<<cdiv(N + 1, 16), 256, 0, stream>>>(x, nullptr, W1, dinv, hs1, N, 0);
    k_gather<<<cdiv(N, 4), 256, 0, stream>>>(hs1, csr, off, dinv, b1, agg1, N);

    // layer 2: hs2 = (relu(agg1) @ W2) * dinv ; agg2 = gather(hs2) + b2 (fp16, pre-relu)
    k_gemm<<<cdiv(N + 1, 16), 256, 0, stream>>>(nullptr, agg1, W2, dinv, hs2, N, 1);
    k_gather<<<cdiv(N, 4), 256, 0, stream>>>(hs2, csr, off, dinv, b2, agg2, N);

    k_pool<<<cdiv(G, 4), 256, 0, stream>>>(agg2, goff, out, G);
}

// Round 14
// 267.279 us; speedup vs baseline: 1.2638x; 1.0078x over previous
//
#include <hip/hip_runtime.h>
#include <hip/hip_fp16.h>

#define DIM 64
#define BIN_SHIFT 7
#define BINSZ 128      // nodes per bin
#define MAXBINS 1024   // supports N up to 131072
#define PB 512         // edge-slice blocks for hist/bucket (power of 2)
#define PB_LOG 9

// ---------------- pass 1: per-block LDS histogram -> C[blk][bin] ----------------

__global__ __launch_bounds__(256) void k_hist(const int* __restrict__ dst,
                                              int* __restrict__ C, int E, int NB) {
    __shared__ int h[MAXBINS];
    for (int i = threadIdx.x; i < NB; i += 256) h[i] = 0;
    __syncthreads();
    int per = (E + PB - 1) / PB;
    int e0 = blockIdx.x * per;
    int e1 = e0 + per; if (e1 > E) e1 = E;
    for (int e = e0 + (int)threadIdx.x; e < e1; e += 256)
        atomicAdd(&h[dst[e] >> BIN_SHIFT], 1);
    __syncthreads();
    for (int i = threadIdx.x; i < NB; i += 256)
        C[blockIdx.x * NB + i] = h[i];
}

// ---------------- pass 2a: chunk-local exclusive scan of C (bin-major order) ----------------
// logical j: bin = j>>PB_LOG, blk = j&(PB-1); S[j] = chunk-local start; bsums[chunk] = total.
// Consumers add bsums[j>>12] inline.

__global__ __launch_bounds__(1024) void k_scanA(const int* __restrict__ C,
                                                int* __restrict__ S,
                                                int* __restrict__ bsums, int NB, int M) {
    __shared__ int sh[1024];
    int tid = threadIdx.x;
    int j0 = blockIdx.x * 4096 + tid * 4;
    int v[4]; int sum = 0;
#pragma unroll
    for (int t = 0; t < 4; ++t) {
        int j = j0 + t; int x = 0;
        if (j < M) { int bin = j >> PB_LOG, blk = j & (PB - 1); x = C[blk * NB + bin]; }
        v[t] = sum; sum += x;
    }
    sh[tid] = sum;
    __syncthreads();
#pragma unroll
    for (int d = 1; d < 1024; d <<= 1) {
        int t = (tid >= d) ? sh[tid - d] : 0;
        __syncthreads();
        sh[tid] += t;
        __syncthreads();
    }
    int excl = sh[tid] - sum;
#pragma unroll
    for (int t = 0; t < 4; ++t) {
        int j = j0 + t;
        if (j < M) S[j] = excl + v[t];
    }
    if (tid == 1023) bsums[blockIdx.x] = sh[1023];
}

// ---------------- pass 2b: exclusive scan of chunk sums ----------------

__global__ __launch_bounds__(1024) void k_scanB(int* __restrict__ bsums, int nb) {
    __shared__ int s[1024];
    int tid = threadIdx.x;
    int v = (tid < nb) ? bsums[tid] : 0;
    s[tid] = v;
    __syncthreads();
#pragma unroll
    for (int d = 1; d < 1024; d <<= 1) {
        int t = (tid >= d) ? s[tid - d] : 0;
        __syncthreads();
        s[tid] += t;
        __syncthreads();
    }
    if (tid < nb) bsums[tid] = s[tid] - v;
}

// ---------------- pass 3: one-pass bucket scatter, LDS cursors ----------------

__global__ __launch_bounds__(256) void k_bucket(const int* __restrict__ src,
                                                const int* __restrict__ dst,
                                                const int* __restrict__ S,
                                                const int* __restrict__ bsums,
                                                int* __restrict__ bkt, int E, int NB) {
    __shared__ int lcur[MAXBINS];
    int blk = blockIdx.x;
    for (int i = threadIdx.x; i < NB; i += 256) {
        int j = i * PB + blk;
        lcur[i] = S[j] + bsums[j >> 12];
    }
    __syncthreads();
    int per = (E + PB - 1) / PB;
    int e0 = blk * per;
    int e1 = e0 + per; if (e1 > E) e1 = E;
    for (int e = e0 + (int)threadIdx.x; e < e1; e += 256) {
        int d = dst[e];
        int pos = atomicAdd(&lcur[d >> BIN_SHIFT], 1);
        bkt[pos] = src[e] | ((d & (BINSZ - 1)) << 24);
    }
}

// ---------------- pass 4: per-bin counting sort (shfl scan) -> csr, off, dinv; + gbound ----------------

__global__ __launch_bounds__(256) void k_binsort(const int* __restrict__ bkt,
                                                 const int* __restrict__ S,
                                                 const int* __restrict__ bsums,
                                                 int* __restrict__ csr,
                                                 int* __restrict__ off,
                                                 float* __restrict__ dinv,
                                                 const int* __restrict__ batch,
                                                 int* __restrict__ goff,
                                                 int N, int G, int E, int NB) {
    __shared__ int cnt[BINSZ], bas[BINSZ], cur[BINSZ];
    __shared__ int wsum[4];
    int tid = threadIdx.x;
    int b = blockIdx.x;
    int j0 = b << PB_LOG;
    int s0 = S[j0] + bsums[j0 >> 12];
    int s1 = E;
    if (b + 1 < NB) { int j1 = (b + 1) << PB_LOG; s1 = S[j1] + bsums[j1 >> 12]; }
    if (tid < BINSZ) { cnt[tid] = 0; cur[tid] = 0; }
    __syncthreads();
    for (int i = s0 + tid; i < s1; i += 256)
        atomicAdd(&cnt[(bkt[i] >> 24) & (BINSZ - 1)], 1);
    __syncthreads();
    int my = (tid < BINSZ) ? cnt[tid] : 0;
    // wave-level inclusive scan + cross-wave fixup
    int lane = tid & 63, wv = tid >> 6;
    int x = my;
#pragma unroll
    for (int d = 1; d < 64; d <<= 1) {
        int t = __shfl_up(x, d);
        if (lane >= d) x += t;
    }
    if (lane == 63) wsum[wv] = x;
    __syncthreads();
    int prefix = 0;
    for (int w = 0; w < wv; ++w) prefix += wsum[w];
    int ex = x + prefix - my;               // exclusive base
    if (tid < BINSZ) {
        bas[tid] = ex;
        int v = (b << BIN_SHIFT) + tid;
        if (v < N) {
            off[v] = s0 + ex;
            dinv[v] = rsqrtf((float)(my + 1));   // +1 self-loop
            if (v == N - 1) off[N] = E;
            // fused gbound (batch sorted)
            int bb = batch[v];
            int prev = (v == 0) ? -1 : batch[v - 1];
            for (int g = prev + 1; g <= bb; ++g) goff[g] = v;
            if (v == N - 1)
                for (int g = bb + 1; g <= G; ++g) goff[g] = N;
        }
    }
    __syncthreads();
    for (int i = s0 + tid; i < s1; i += 256) {
        int p = bkt[i];
        int lo = (p >> 24) & (BINSZ - 1);
        int li = atomicAdd(&cur[lo], 1);
        csr[s0 + bas[lo] + li] = p & 0xFFFFFF;
    }
}

// ---------------- skinny GEMM: hs[row] = (act(X[row]) @ W) * dinv[row] (fp16 out) ----------------

__global__ __launch_bounds__(256) void k_gemm(const float* __restrict__ Xf,
                                              const __half* __restrict__ Xh,
                                              const float* __restrict__ W,
                                              const float* __restrict__ dinv,
                                              __half* __restrict__ Y, int N, int relu_in) {
    __shared__ float Ws[64 * 64];
    __shared__ float Xs[16 * 64];
    int tid = threadIdx.x;
#pragma unroll
    for (int i = 0; i < 16; ++i) Ws[tid + 256 * i] = W[tid + 256 * i];

    int row0 = blockIdx.x * 16;
    int r = tid >> 4, c4 = (tid & 15) << 2;
    int row = row0 + r;
    {
        float4 v = make_float4(0.f, 0.f, 0.f, 0.f);
        if (row < N) {
            if (Xh) {
                uint2 u = *(const uint2*)(Xh + (size_t)row * DIM + c4);
                float2 f0 = __half22float2(*(__half2*)&u.x);
                float2 f1 = __half22float2(*(__half2*)&u.y);
                v = make_float4(f0.x, f0.y, f1.x, f1.y);
            } else {
                v = *(const float4*)(Xf + (size_t)row * DIM + c4);
            }
            if (relu_in) {
                v.x = fmaxf(v.x, 0.f); v.y = fmaxf(v.y, 0.f);
                v.z = fmaxf(v.z, 0.f); v.w = fmaxf(v.w, 0.f);
            }
        }
        *(float4*)(Xs + r * DIM + c4) = v;
    }
    __syncthreads();

    float4 acc = make_float4(0.f, 0.f, 0.f, 0.f);
#pragma unroll
    for (int k = 0; k < 64; ++k) {
        float xk = Xs[r * DIM + k];
        float4 w = *(const float4*)(Ws + k * DIM + c4);
        acc.x += xk * w.x; acc.y += xk * w.y;
        acc.z += xk * w.z; acc.w += xk * w.w;
    }
    if (row < N) {
        float s = dinv[row];
        __half2 p0 = __floats2half2_rn(acc.x * s, acc.y * s);
        __half2 p1 = __floats2half2_rn(acc.z * s, acc.w * s);
        uint2 u;
        u.x = *(unsigned int*)&p0;
        u.y = *(unsigned int*)&p1;
        *(uint2*)(Y + (size_t)row * DIM + c4) = u;
    } else if (row == N) {
        uint2 z; z.x = 0u; z.y = 0u;
        *(uint2*)(Y + (size_t)row * DIM + c4) = z;
    }
}

// ---------------- gather: agg[v] = dv*(hs[v] + sum hs[nbr]) + bias (fp16 out, pre-relu) ----------------
// one 64-lane wave per node; 8-lane groups x uint4 (16B) cover a row; 16 edges/iter, dual acc

__global__ __launch_bounds__(256) void k_gather(const __half* __restrict__ hs,
                                                const int* __restrict__ csr_src,
                                                const int* __restrict__ off,
                                                const float* __restrict__ dinv,
                                                const float* __restrict__ bias,
                                                __half* __restrict__ agg, int N) {
    int v = (blockIdx.x * 256 + threadIdx.x) >> 6;
    int lane = threadIdx.x & 63;
    if (v >= N) return;
    int g = lane >> 3, c = lane & 7;
    const uint4* h4 = (const uint4*)hs;   // 8 uint4 per 64-half row

    float4 aX0 = make_float4(0.f, 0.f, 0.f, 0.f), aX1 = aX0;
    float4 aY0 = aX0, aY1 = aX0;
    if (g == 0) {                          // self-loop term hs[v]
        uint4 u = h4[(size_t)v * 8 + c];
        float2 f0 = __half22float2(*(__half2*)&u.x);
        float2 f1 = __half22float2(*(__half2*)&u.y);
        float2 f2 = __half22float2(*(__half2*)&u.z);
        float2 f3 = __half22float2(*(__half2*)&u.w);
        aX0 = make_float4(f0.x, f0.y, f1.x, f1.y);
        aX1 = make_float4(f2.x, f2.y, f3.x, f3.y);
    }

    int k0 = off[v], k1 = off[v + 1];
    for (int kb = k0; kb < k1; kb += 64) {
        int m = k1 - kb;
        int idx = N;                       // zero row for padding lanes
        if (lane < m) idx = csr_src[kb + lane];
        int mlim = m > 64 ? 64 : m;
        int mm = (mlim + 15) & ~15;
        for (int j = 0; j < mm; j += 16) { // 16 edges per iter: 2 16B gathers in flight
            int sA = __shfl(idx, j + g);
            int sB = __shfl(idx, j + 8 + g);
            uint4 uA = h4[(size_t)sA * 8 + c];
            uint4 uB = h4[(size_t)sB * 8 + c];
            {
                float2 t0 = __half22float2(*(__half2*)&uA.x);
                float2 t1 = __half22float2(*(__half2*)&uA.y);
                float2 t2 = __half22float2(*(__half2*)&uA.z);
                float2 t3 = __half22float2(*(__half2*)&uA.w);
                aX0.x += t0.x; aX0.y += t0.y; aX0.z += t1.x; aX0.w += t1.y;
                aX1.x += t2.x; aX1.y += t2.y; aX1.z += t3.x; aX1.w += t3.y;
            }
            {
                float2 t0 = __half22float2(*(__half2*)&uB.x);
                float2 t1 = __half22float2(*(__half2*)&uB.y);
                float2 t2 = __half22float2(*(__half2*)&uB.z);
                float2 t3 = __half22float2(*(__half2*)&uB.w);
                aY0.x += t0.x; aY0.y += t0.y; aY0.z += t1.x; aY0.w += t1.y;
                aY1.x += t2.x; aY1.y += t2.y; aY1.z += t3.x; aY1.w += t3.y;
            }
        }
    }
    float4 a0 = make_float4(aX0.x + aY0.x, aX0.y + aY0.y, aX0.z + aY0.z, aX0.w + aY0.w);
    float4 a1 = make_float4(aX1.x + aY1.x, aX1.y + aY1.y, aX1.z + aY1.z, aX1.w + aY1.w);
    // reduce 8 groups: lanes (c, 8+c, ..., 56+c) -> lane c
#pragma unroll
    for (int d = 32; d >= 8; d >>= 1) {
        a0.x += __shfl_down(a0.x, d); a0.y += __shfl_down(a0.y, d);
        a0.z += __shfl_down(a0.z, d); a0.w += __shfl_down(a0.w, d);
        a1.x += __shfl_down(a1.x, d); a1.y += __shfl_down(a1.y, d);
        a1.z += __shfl_down(a1.z, d); a1.w += __shfl_down(a1.w, d);
    }
    if (g == 0) {
        float dv = dinv[v];
        const float4* b4 = (const float4*)bias;
        float4 bv0 = b4[2 * c], bv1 = b4[2 * c + 1];
        __half2 p0 = __floats2half2_rn(a0.x * dv + bv0.x, a0.y * dv + bv0.y);
        __half2 p1 = __floats2half2_rn(a0.z * dv + bv0.z, a0.w * dv + bv0.w);
        __half2 p2 = __floats2half2_rn(a1.x * dv + bv1.x, a1.y * dv + bv1.y);
        __half2 p3 = __floats2half2_rn(a1.z * dv + bv1.z, a1.w * dv + bv1.w);
        uint4 u;
        u.x = *(unsigned int*)&p0; u.y = *(unsigned int*)&p1;
        u.z = *(unsigned int*)&p2; u.w = *(unsigned int*)&p3;
        ((uint4*)(agg + (size_t)v * DIM))[c] = u;
    }
}

// ---------------- pool: out[g] = mean relu(agg2[v]) (fp16 input) ----------------

__global__ __launch_bounds__(256) void k_pool(const __half* __restrict__ agg,
                                              const int* __restrict__ goff,
                                              float* __restrict__ out, int G) {
    int g = blockIdx.x * 4 + (threadIdx.x >> 6);
    if (g >= G) return;
    int lane = threadIdx.x & 63;
    int q = lane >> 4, c = lane & 15;
    const uint2* h2 = (const uint2*)agg;
    int n0 = goff[g], n1 = goff[g + 1];
    float4 acc = make_float4(0.f, 0.f, 0.f, 0.f);
    for (int i = n0 + q; i < n1; i += 4) {
        uint2 u = h2[(size_t)i * 16 + c];
        float2 f0 = __half22float2(*(__half2*)&u.x);
        float2 f1 = __half22float2(*(__half2*)&u.y);
        acc.x += fmaxf(f0.x, 0.f); acc.y += fmaxf(f0.y, 0.f);
        acc.z += fmaxf(f1.x, 0.f); acc.w += fmaxf(f1.y, 0.f);
    }
    acc.x += __shfl_down(acc.x, 32); acc.y += __shfl_down(acc.y, 32);
    acc.z += __shfl_down(acc.z, 32); acc.w += __shfl_down(acc.w, 32);
    acc.x += __shfl_down(acc.x, 16); acc.y += __shfl_down(acc.y, 16);
    acc.z += __shfl_down(acc.z, 16); acc.w += __shfl_down(acc.w, 16);
    if (q == 0) {
        float inv = 1.0f / fmaxf((float)(n1 - n0), 1.0f);
        *(float4*)(out + ((size_t)g << 6) + (c << 2)) =
            make_float4(acc.x * inv, acc.y * inv, acc.z * inv, acc.w * inv);
    }
}

// ---------------- launch ----------------

static inline int cdiv(int a, int b) { return (a + b - 1) / b; }

extern "C" void kernel_launch(void* const* d_in, const int* in_sizes, int n_in,
                              void* d_out, int out_size, void* d_ws, size_t ws_size,
                              hipStream_t stream) {
    const float* x   = (const float*)d_in[0];
    const float* W1  = (const float*)d_in[1];
    const float* b1  = (const float*)d_in[2];
    const float* W2  = (const float*)d_in[3];
    const float* b2  = (const float*)d_in[4];
    const int*   ei  = (const int*)d_in[5];
    const int*   bat = (const int*)d_in[6];

    const int N = in_sizes[0] / DIM;
    const int E = in_sizes[5] / 2;
    const int G = out_size / DIM;
    const int NB = cdiv(N, BINSZ);           // <= MAXBINS
    const int M  = NB * PB;                  // scan length
    const int* src = ei;
    const int* dst = ei + E;
    float* out = (float*)d_out;

    // workspace: hs1 | hs2 | agg1 | dinv | off | goff | C | S | bsums | csr
    // bkt aliases hs1 (dead before gemm1); agg2 aliases hs1 (dead after gather1).
    __half* hs1    = (__half*)d_ws;                         // (N+1)*64 h
    __half* hs2    = hs1 + (size_t)(N + 1) * DIM;           // (N+1)*64 h
    __half* agg1   = hs2 + (size_t)(N + 1) * DIM;           // N*64 h
    float*  dinv   = (float*)(agg1 + (size_t)N * DIM);      // N f
    int*    off    = (int*)(dinv + N);                      // N+1 i
    int*    goff   = off + (N + 1);                         // G+1 i
    int*    C      = goff + (G + 1);                        // PB*NB i
    int*    S      = C + (size_t)PB * NB;                   // PB*NB i
    int*    bsums  = S + (size_t)PB * NB;                   // up to 1024 i
    int*    csr    = bsums + 1024;                          // E i
    int*    bkt    = (int*)hs1;                             // E i (aliased)
    __half* agg2   = hs1;                                   // N*64 h (aliased)

    k_hist<<<PB, 256, 0, stream>>>(dst, C, E, NB);
    int nb2 = cdiv(M, 4096);
    k_scanA<<<nb2, 1024, 0, stream>>>(C, S, bsums, NB, M);
    k_scanB<<<1, 1024, 0, stream>>>(bsums, nb2);
    k_bucket<<<PB, 256, 0, stream>>>(src, dst, S, bsums, bkt, E, NB);
    k_binsort<<<NB, 256, 0, stream>>>(bkt, S, bsums, csr, off, dinv, bat, goff, N, G, E, NB);

    // layer 1: hs1 = (x @ W1) * dinv ; agg1 = gather(hs1) + b1 (fp16, pre-relu)
    k_gemm<<<cdiv(N + 1, 16), 256, 0, stream>>>(x, nullptr, W1, dinv, hs1, N, 0);
    k_gather<<<cdiv(N, 4), 256, 0, stream>>>(hs1, csr, off, dinv, b1, agg1, N);

    // layer 2: hs2 = (relu(agg1) @ W2) * dinv ; agg2 = gather(hs2) + b2 (fp16, pre-relu)
    k_gemm<<<cdiv(N + 1, 16), 256, 0, stream>>>(nullptr, agg1, W2, dinv, hs2, N, 1);
    k_gather<<<cdiv(N, 4), 256, 0, stream>>>(hs2, csr, off, dinv, b2, agg2, N);

    k_pool<<<cdiv(G, 4), 256, 0, stream>>>(agg2, goff, out, G);
}